// Round 8
// baseline (141.172 us; speedup 1.0000x reference)
//
#include <hip/hip_runtime.h>

#define Bn 4
#define Nn 2048
#define NBn 10
#define BN (Bn*Nn)
#define TCOLS 256     // gt columns per block (4 per lane, shared by all 4 waves)
#define NCH 64        // pred rows per block (16 per wave)
#define BIGM 1e32f

// ws layout in float (4-byte) units  (sym cloud eliminated: it's gt with pts 2<->3 swapped)
#define OFF_PRED 0
#define OFF_GT   (BN*16)
#define OFF_PN2  (2*BN*16)
#define OFF_GN2  (OFF_PN2 + BN)
#define OFF_BEST (OFF_GN2 + BN)      // u32 per (b,n): forward min dist (fp32 bits)
#define OFF_PK   (OFF_BEST + BN)     // u32 per (b,m): (dist&0xFFFFF000)|(mat<<11)|n
#define OFF_PART (OFF_PK + BN)       // 32 records x 8 floats: 0=dir 1=app 2=off 3=pos 4=bce 5=adds 6=g2p

__device__ inline float sp_(float x) {            // jax.nn.softplus, stable form
  return fmaxf(x, 0.0f) + log1pf(expf(-fabsf(x)));
}

// wave64 min-reduce on the VALU pipe (DPP), no DS ops. Result valid in lane 63.
__device__ inline float waveMin_(float v) {
  const int INFI = 0x7F800000;
#define DPPMIN(ctrl) \
  v = fminf(v, __int_as_float(__builtin_amdgcn_update_dpp(INFI, __float_as_int(v), ctrl, 0xf, 0xf, false)))
  DPPMIN(0x111);  // row_shr:1
  DPPMIN(0x112);  // row_shr:2
  DPPMIN(0x114);  // row_shr:4
  DPPMIN(0x118);  // row_shr:8   -> lane15 of each row16 holds row min
  DPPMIN(0x142);  // row_bcast:15
  DPPMIN(0x143);  // row_bcast:31 -> lane63 holds wave min
#undef DPPMIN
  return v;
}

__device__ inline float blockSum_(float v, float* red) {
  #pragma unroll
  for (int o = 32; o > 0; o >>= 1) v += __shfl_down(v, o, 64);
  __syncthreads();
  if ((threadIdx.x & 63) == 0) red[threadIdx.x >> 6] = v;
  __syncthreads();
  return red[0] + red[1] + red[2] + red[3];
}

// ---------- prep: frames, control points, norms, min-state init, cheap per-point
// loss partials. grid (BN/256) = 32, block 256.
__global__ __launch_bounds__(256) void k_prep(
    const float* __restrict__ gdir, const float* __restrict__ adirp,
    const float* __restrict__ goff, const float* __restrict__ ppts,
    const float* __restrict__ bsh,
    const float* __restrict__ dlab, const float* __restrict__ olab,
    const float* __restrict__ succ, const float* __restrict__ alab,
    const float* __restrict__ binv, const float* __restrict__ binw,
    const float* __restrict__ cpts, const float* __restrict__ scpts,
    float* __restrict__ ws)
{
  __shared__ float red[4];
  const int pb = blockIdx.x;
  const int idx = pb * 256 + threadIdx.x;

  const float gd0=gdir[idx*3+0],  gd1=gdir[idx*3+1],  gd2=gdir[idx*3+2];
  const float ad0=adirp[idx*3+0], ad1=adirp[idx*3+1], ad2=adirp[idx*3+2];
  const float dl0=dlab[idx*3+0],  dl1=dlab[idx*3+1],  dl2=dlab[idx*3+2];
  const float al0=alab[idx*3+0],  al1=alab[idx*3+1],  al2=alab[idx*3+2];
  const float pt0=ppts[idx*3+0],  pt1=ppts[idx*3+1],  pt2=ppts[idx*3+2];
  const float sc = succ[idx];

  // argmax (first occurrence, matches jnp.argmax)
  float bv = goff[idx*NBn]; int ap = 0;
  #pragma unroll
  for (int k = 1; k < NBn; k++) { float v = goff[idx*NBn+k]; if (v > bv) { bv = v; ap = k; } }
  float bg = olab[idx*NBn]; int ag = 0;
  #pragma unroll
  for (int k = 1; k < NBn; k++) { float v = olab[idx*NBn+k]; if (v > bg) { bg = v; ag = k; } }
  const float tp = binv[ap] * 0.5f;
  const float tg = binv[ag] * 0.5f;

  // frames: cross = cross(approach, base); t = pt + 0.5*thickness*base
  const float cp0 = ad1*gd2 - ad2*gd1, cp1 = ad2*gd0 - ad0*gd2, cp2 = ad0*gd1 - ad1*gd0;
  const float cg0 = al1*dl2 - al2*dl1, cg1 = al2*dl0 - al0*dl2, cg2 = al0*dl1 - al1*dl0;
  const float tpx = pt0 + tp*gd0, tpy = pt1 + tp*gd1, tpz = pt2 + tp*gd2;
  const float tgx = pt0 + tg*dl0, tgy = pt1 + tg*dl1, tgz = pt2 + tg*dl2;

  float pcp[15], gcp[15];
  float pn2 = 0.f, gn2 = 0.f;
  #pragma unroll
  for (int p = 0; p < 5; p++) {
    const float cx = cpts[p*3], cy = cpts[p*3+1], cz = cpts[p*3+2];
    float x, y, z;
    x = gd0*cx + cp0*cy + ad0*cz + tpx;
    y = gd1*cx + cp1*cy + ad1*cz + tpy;
    z = gd2*cx + cp2*cy + ad2*cz + tpz;
    pcp[p*3+0]=x; pcp[p*3+1]=y; pcp[p*3+2]=z;
    pn2 = fmaf(x,x, fmaf(y,y, fmaf(z,z, pn2)));
    x = dl0*cx + cg0*cy + al0*cz + tgx;
    y = dl1*cx + cg1*cy + al1*cz + tgy;
    z = dl2*cx + cg2*cy + al2*cz + tgz;
    gcp[p*3+0]=x; gcp[p*3+1]=y; gcp[p*3+2]=z;
    gn2 = fmaf(x,x, fmaf(y,y, fmaf(z,z, gn2)));
  }

  float4* pd = (float4*)(ws + OFF_PRED) + (size_t)idx*4;
  pd[0]=make_float4(pcp[0],pcp[1],pcp[2],pcp[3]);
  pd[1]=make_float4(pcp[4],pcp[5],pcp[6],pcp[7]);
  pd[2]=make_float4(pcp[8],pcp[9],pcp[10],pcp[11]);
  pd[3]=make_float4(pcp[12],pcp[13],pcp[14],0.f);
  float4* gdst = (float4*)(ws + OFF_GT) + (size_t)idx*4;
  gdst[0]=make_float4(gcp[0],gcp[1],gcp[2],gcp[3]);
  gdst[1]=make_float4(gcp[4],gcp[5],gcp[6],gcp[7]);
  gdst[2]=make_float4(gcp[8],gcp[9],gcp[10],gcp[11]);
  gdst[3]=make_float4(gcp[12],gcp[13],gcp[14],0.f);
  ws[OFF_PN2+idx] = pn2; ws[OFF_GN2+idx] = gn2;

  // per-idx min-state init (k_pair runs strictly after)
  ((unsigned*)ws)[OFF_BEST + idx] = 0x7F800000u;   // +inf
  ((unsigned*)ws)[OFF_PK   + idx] = 0xFFFFFFFFu;

  // ---- cheap per-point losses -> per-block partials ----
  const float cosd = 1.f - (dl0*gd0 + dl1*gd1 + dl2*gd2);
  const float proj = gd0*al0 + gd1*al1 + gd2*al2;
  const float o0 = al0 - proj*gd0, o1 = al1 - proj*gd1, o2 = al2 - proj*gd2;
  const float on = sqrtf(o0*o0 + o1*o1 + o2*o2);
  const float inv = 1.f / fmaxf(on, 1e-12f);
  const float cosa = 1.f - inv*(o0*ad0 + o1*ad1 + o2*ad2);

  float offv = 0.f;
  #pragma unroll
  for (int k = 0; k < NBn; k++) {
    const float x = goff[idx*NBn+k], lab = olab[idx*NBn+k];
    const float bce = lab * sp_(-x) + (1.f - lab) * sp_(x);
    offv = fmaf(binw[k], bce, offv);
  }
  offv *= (1.0f / NBn);
  const float sb = bsh[idx];
  const float sbce = sc * sp_(-sb) + (1.f - sc) * sp_(sb);

  float* part = ws + OFF_PART + (size_t)pb*8;
  float t;
  t = blockSum_(cosd*sc, red); if (threadIdx.x == 0) part[0] = t;
  t = blockSum_(cosa*sc, red); if (threadIdx.x == 0) part[1] = t;
  t = blockSum_(offv*sc, red); if (threadIdx.x == 0) part[2] = t;
  t = blockSum_(sc, red);      if (threadIdx.x == 0) part[3] = t;
  t = blockSum_(sbce, red);    if (threadIdx.x == 0) part[4] = t;
}

// ---------- single-pass pairwise kernel. grid (Nn/TCOLS, Nn/NCH, Bn) = (8,32,4), block 256.
// Each lane owns 4 gt columns in registers. Sym distances via the permutation identity
// (sym = gt with pts 2<->3 swapped): dot_sym = dot_gt + (p[6..8]-p[9..11]).(g[9..11]-g[6..8]).
// Pred rows staged in LDS, read per-j at wave-uniform addresses (broadcast ds_read_b128).
// Forward row-min uses the DPP reduction (VALU pipe) — no shfl/DS butterfly.
__global__ __launch_bounds__(256, 4) void k_pair(const float* __restrict__ succ,
                                                 float* __restrict__ ws) {
  __shared__ float pls[NCH*16];       // 64 pred rows x 16 floats
  __shared__ float pn2s[NCH];
  __shared__ unsigned bkey[TCOLS];
  const int tile = blockIdx.x * TCOLS, b = blockIdx.z;
  const int bN = b * Nn;
  const int ny0 = blockIdx.y * NCH;
  const int tid = threadIdx.x;
  const int lane = tid & 63;
  const int wid = __builtin_amdgcn_readfirstlane(tid >> 6);

  // stage pred rows: 256 threads x 1 float4 = 64 rows x 16 floats
  {
    const int row = tid >> 2, q = tid & 3;
    ((float4*)pls)[tid] = ((const float4*)(ws + OFF_PRED))[(size_t)(bN + ny0 + row)*4 + q];
    if (tid < NCH) pn2s[tid] = ws[OFF_PN2 + bN + ny0 + tid];
    bkey[tid] = 0xFFFFFFFFu;
  }

  // lane's four columns (registers)
  float4 gq[4][4];
  float  gnc[4], biasc[4], ex[4], ey[4], ez[4];
  unsigned kk[4];
  const float4* G = (const float4*)(ws + OFF_GT);
  #pragma unroll
  for (int c = 0; c < 4; c++) {
    const int r = bN + tile + c*64 + lane;
    gq[c][0] = G[(size_t)r*4+0]; gq[c][1] = G[(size_t)r*4+1];
    gq[c][2] = G[(size_t)r*4+2]; gq[c][3] = G[(size_t)r*4+3];
    gnc[c]   = ws[OFF_GN2 + r];
    biasc[c] = (succ[r] != 0.f) ? 0.f : BIGM;
    // sym-delta fragments: g[9..11] - g[6..8]
    ex[c] = gq[c][2].y - gq[c][1].z;
    ey[c] = gq[c][2].z - gq[c][1].w;
    ez[c] = gq[c][2].w - gq[c][2].x;
    kk[c] = 0xFFFFFFFFu;
  }

  float f[16];
  __syncthreads();

  const float4* PL = (const float4*)pls + (size_t)wid*16*4;   // this wave's 16 rows

  #pragma unroll
  for (int j = 0; j < 16; j++) {
    const float4 p0 = PL[j*4+0], p1 = PL[j*4+1], p2 = PL[j*4+2], p3 = PL[j*4+3];
    const float pn2 = pn2s[wid*16 + j];
    const float pd0 = p1.z - p2.y, pd1 = p1.w - p2.z, pd2 = p2.x - p2.w;
    const unsigned nl = (unsigned)(ny0 + wid*16 + j), nh = nl | 0x800u;

    float fj = BIGM * 2.f;
    #pragma unroll
    for (int c = 0; c < 4; c++) {
      float s;
      s = fmaf(p0.w, gq[c][0].w, fmaf(p0.z, gq[c][0].z, fmaf(p0.y, gq[c][0].y, p0.x*gq[c][0].x)));
      s = fmaf(p1.w, gq[c][1].w, fmaf(p1.z, gq[c][1].z, fmaf(p1.y, gq[c][1].y, fmaf(p1.x, gq[c][1].x, s))));
      s = fmaf(p2.w, gq[c][2].w, fmaf(p2.z, gq[c][2].z, fmaf(p2.y, gq[c][2].y, fmaf(p2.x, gq[c][2].x, s))));
      const float dot = fmaf(p3.z, gq[c][3].z, fmaf(p3.y, gq[c][3].y, fmaf(p3.x, gq[c][3].x, s)));
      const float del = fmaf(pd0, ex[c], fmaf(pd1, ey[c], pd2*ez[c]));
      const float q1  = fmaf(-2.f, dot, pn2 + gnc[c]);
      const float d1  = fmaxf(q1, 0.f);
      const float d2  = fmaxf(fmaf(-2.f, del, q1), 0.f);

      // backward packed key: (dist&0xFFFFF000)|(mat<<11)|n — u32 min is lexicographic
      // (d, mat, n): d-tie -> mat0 (= reference i1-on-tie), then first n.
      kk[c] = min(kk[c], min((__float_as_uint(d1) & 0xFFFFF000u) | nl,
                             (__float_as_uint(d2) & 0xFFFFF000u) | nh));

      fj = fminf(fj, fminf(d1, d2) + biasc[c]);
    }
    f[j] = fj;
  }

  // forward: 16 independent DPP wave-min chains (VALU pipe); lane 63 owns results
  #pragma unroll
  for (int j = 0; j < 16; j++) f[j] = waveMin_(f[j]);
  if (lane == 63) {
    #pragma unroll
    for (int j = 0; j < 16; j++)
      atomicMin((unsigned*)ws + OFF_BEST + bN + ny0 + wid*16 + j, __float_as_uint(f[j]));
  }

  // merge the 4 waves' backward keys (same columns, disjoint n) then one global atomic/col
  #pragma unroll
  for (int c = 0; c < 4; c++) atomicMin(&bkey[c*64 + lane], kk[c]);
  __syncthreads();
  atomicMin((unsigned*)ws + OFF_PK + bN + tile + tid, bkey[tid]);
}

// ---------- reduce: adds/g2p per-block partials. grid (Nn/256, Bn) = (8,4), block 256.
__global__ __launch_bounds__(256) void k_red(const float* __restrict__ bsp,
                                             const float* __restrict__ succ,
                                             float* __restrict__ ws) {
  __shared__ float red[4];
  const int b = blockIdx.y, nt = blockIdx.x;
  const int idx = b*Nn + nt*256 + threadIdx.x;

  const float best = __uint_as_float(((const unsigned*)ws)[OFF_BEST + idx]);
  const float adds = (best < 1e30f) ? bsp[idx] * sqrtf(best) : 0.f;  // >=1e30 <=> no positives -> gate 0

  const unsigned key = ((const unsigned*)ws)[OFF_PK + idx];
  const float d = __uint_as_float(key & 0xFFFFF000u);
  const int  id = (int)(key & 0x7FFu);
  const float g2p = bsp[b*Nn + id] * d * succ[idx];

  float* part = ws + OFF_PART + (size_t)(b*8 + nt)*8;
  float t;
  t = blockSum_(adds, red); if (threadIdx.x == 0) part[5] = t;
  t = blockSum_(g2p, red);  if (threadIdx.x == 0) part[6] = t;
}

// ---------- finalize: 1 block, 64 threads, wave-only reduction of 32x7 partials
__global__ __launch_bounds__(64) void k_fin(const float* __restrict__ ws, float* __restrict__ out) {
  const int t = threadIdx.x;
  float v[7];
  #pragma unroll
  for (int c = 0; c < 7; c++) v[c] = (t < 32) ? ws[OFF_PART + t*8 + c] : 0.f;
  #pragma unroll
  for (int o = 1; o < 8; o <<= 1) {
    #pragma unroll
    for (int c = 0; c < 7; c++) v[c] += __shfl_xor(v[c], o, 64);
  }
  // each 8-lane group (t<32) now holds per-b sums (b = t>>3)
  const float pos = fmaxf(v[3], 1.f);
  float vb   = (v[0] + v[1] + v[2] + v[6]) / pos;   // dir + app + off + g2p, per-b normalized
  float bce  = v[4];
  float adds = v[5];
  #pragma unroll
  for (int o = 8; o < 32; o <<= 1) {
    vb   += __shfl_xor(vb,   o, 64);
    bce  += __shfl_xor(bce,  o, 64);
    adds += __shfl_xor(adds, o, 64);
  }
  if (t == 0)
    out[0] = vb * 0.25f + bce * (1.f/BN) + 10.f * adds * (1.f/BN);
}

extern "C" void kernel_launch(void* const* d_in, const int* in_sizes, int n_in,
                              void* d_out, int out_size, void* d_ws, size_t ws_size,
                              hipStream_t stream) {
  const float* gdir  = (const float*)d_in[0];
  const float* adirp = (const float*)d_in[1];
  const float* goff  = (const float*)d_in[2];
  const float* ppts  = (const float*)d_in[3];
  const float* bsp   = (const float*)d_in[4];
  const float* bsh   = (const float*)d_in[5];
  const float* dlab  = (const float*)d_in[6];
  const float* olab  = (const float*)d_in[7];
  const float* succ  = (const float*)d_in[8];
  const float* alab  = (const float*)d_in[9];
  const float* binv  = (const float*)d_in[10];
  const float* binw  = (const float*)d_in[11];
  const float* cpts  = (const float*)d_in[12];
  const float* scpts = (const float*)d_in[13];
  float* ws  = (float*)d_ws;
  float* out = (float*)d_out;
  (void)scpts;

  k_prep<<<dim3(BN/256), dim3(256), 0, stream>>>(gdir, adirp, goff, ppts, bsh,
                                                 dlab, olab, succ, alab,
                                                 binv, binw, cpts, scpts, ws);
  k_pair<<<dim3(Nn/TCOLS, Nn/NCH, Bn), dim3(256), 0, stream>>>(succ, ws);
  k_red<<<dim3(Nn/256, Bn), dim3(256), 0, stream>>>(bsp, succ, ws);
  k_fin<<<1, 64, 0, stream>>>(ws, out);
}

// Round 9
// 116.495 us; speedup vs baseline: 1.2118x; 1.2118x over previous
//
#include <hip/hip_runtime.h>

#define Bn 4
#define Nn 2048
#define NBn 10
#define BN (Bn*Nn)
#define TCOLS 256     // gt columns per block (4 per lane, shared by all 4 waves)
#define NCH 64        // pred rows per block (16 per wave)
#define BIGM 1e32f

// ws layout in float (4-byte) units  (sym cloud eliminated: it's gt with pts 2<->3 swapped)
#define OFF_PRED 0
#define OFF_GT   (BN*16)
#define OFF_PN2  (2*BN*16)
#define OFF_GN2  (OFF_PN2 + BN)
#define OFF_BEST (OFF_GN2 + BN)      // u32 per (b,n): forward min dist (fp32 bits)
#define OFF_PK   (OFF_BEST + BN)     // u32 per (b,m): (dist&0xFFFFF000)|(mat<<11)|n
#define OFF_PART (OFF_PK + BN)       // 32 records x 8 floats: 0=dir 1=app 2=off 3=pos 4=bce 5=adds 6=g2p

__device__ inline float sp_(float x) {            // jax.nn.softplus, stable form
  return fmaxf(x, 0.0f) + log1pf(expf(-fabsf(x)));
}

// wave64 min-reduce on the VALU pipe (DPP), no DS ops. Result valid in lane 63.
__device__ inline float waveMin_(float v) {
  const int INFI = 0x7F800000;
#define DPPMIN(ctrl) \
  v = fminf(v, __int_as_float(__builtin_amdgcn_update_dpp(INFI, __float_as_int(v), ctrl, 0xf, 0xf, false)))
  DPPMIN(0x111);  // row_shr:1
  DPPMIN(0x112);  // row_shr:2
  DPPMIN(0x114);  // row_shr:4
  DPPMIN(0x118);  // row_shr:8   -> lane15 of each row16 holds row min
  DPPMIN(0x142);  // row_bcast:15
  DPPMIN(0x143);  // row_bcast:31 -> lane63 holds wave min
#undef DPPMIN
  return v;
}

__device__ inline float blockSum_(float v, float* red) {
  #pragma unroll
  for (int o = 32; o > 0; o >>= 1) v += __shfl_down(v, o, 64);
  __syncthreads();
  if ((threadIdx.x & 63) == 0) red[threadIdx.x >> 6] = v;
  __syncthreads();
  return red[0] + red[1] + red[2] + red[3];
}

// ---------- prep: frames, control points, norms, min-state init, cheap per-point
// loss partials. grid (BN/256) = 32, block 256.
__global__ __launch_bounds__(256) void k_prep(
    const float* __restrict__ gdir, const float* __restrict__ adirp,
    const float* __restrict__ goff, const float* __restrict__ ppts,
    const float* __restrict__ bsh,
    const float* __restrict__ dlab, const float* __restrict__ olab,
    const float* __restrict__ succ, const float* __restrict__ alab,
    const float* __restrict__ binv, const float* __restrict__ binw,
    const float* __restrict__ cpts, const float* __restrict__ scpts,
    float* __restrict__ ws)
{
  __shared__ float red[4];
  const int pb = blockIdx.x;
  const int idx = pb * 256 + threadIdx.x;

  const float gd0=gdir[idx*3+0],  gd1=gdir[idx*3+1],  gd2=gdir[idx*3+2];
  const float ad0=adirp[idx*3+0], ad1=adirp[idx*3+1], ad2=adirp[idx*3+2];
  const float dl0=dlab[idx*3+0],  dl1=dlab[idx*3+1],  dl2=dlab[idx*3+2];
  const float al0=alab[idx*3+0],  al1=alab[idx*3+1],  al2=alab[idx*3+2];
  const float pt0=ppts[idx*3+0],  pt1=ppts[idx*3+1],  pt2=ppts[idx*3+2];
  const float sc = succ[idx];

  // argmax (first occurrence, matches jnp.argmax)
  float bv = goff[idx*NBn]; int ap = 0;
  #pragma unroll
  for (int k = 1; k < NBn; k++) { float v = goff[idx*NBn+k]; if (v > bv) { bv = v; ap = k; } }
  float bg = olab[idx*NBn]; int ag = 0;
  #pragma unroll
  for (int k = 1; k < NBn; k++) { float v = olab[idx*NBn+k]; if (v > bg) { bg = v; ag = k; } }
  const float tp = binv[ap] * 0.5f;
  const float tg = binv[ag] * 0.5f;

  // frames: cross = cross(approach, base); t = pt + 0.5*thickness*base
  const float cp0 = ad1*gd2 - ad2*gd1, cp1 = ad2*gd0 - ad0*gd2, cp2 = ad0*gd1 - ad1*gd0;
  const float cg0 = al1*dl2 - al2*dl1, cg1 = al2*dl0 - al0*dl2, cg2 = al0*dl1 - al1*dl0;
  const float tpx = pt0 + tp*gd0, tpy = pt1 + tp*gd1, tpz = pt2 + tp*gd2;
  const float tgx = pt0 + tg*dl0, tgy = pt1 + tg*dl1, tgz = pt2 + tg*dl2;

  float pcp[15], gcp[15];
  float pn2 = 0.f, gn2 = 0.f;
  #pragma unroll
  for (int p = 0; p < 5; p++) {
    const float cx = cpts[p*3], cy = cpts[p*3+1], cz = cpts[p*3+2];
    float x, y, z;
    x = gd0*cx + cp0*cy + ad0*cz + tpx;
    y = gd1*cx + cp1*cy + ad1*cz + tpy;
    z = gd2*cx + cp2*cy + ad2*cz + tpz;
    pcp[p*3+0]=x; pcp[p*3+1]=y; pcp[p*3+2]=z;
    pn2 = fmaf(x,x, fmaf(y,y, fmaf(z,z, pn2)));
    x = dl0*cx + cg0*cy + al0*cz + tgx;
    y = dl1*cx + cg1*cy + al1*cz + tgy;
    z = dl2*cx + cg2*cy + al2*cz + tgz;
    gcp[p*3+0]=x; gcp[p*3+1]=y; gcp[p*3+2]=z;
    gn2 = fmaf(x,x, fmaf(y,y, fmaf(z,z, gn2)));
  }

  float4* pd = (float4*)(ws + OFF_PRED) + (size_t)idx*4;
  pd[0]=make_float4(pcp[0],pcp[1],pcp[2],pcp[3]);
  pd[1]=make_float4(pcp[4],pcp[5],pcp[6],pcp[7]);
  pd[2]=make_float4(pcp[8],pcp[9],pcp[10],pcp[11]);
  pd[3]=make_float4(pcp[12],pcp[13],pcp[14],0.f);
  float4* gdst = (float4*)(ws + OFF_GT) + (size_t)idx*4;
  gdst[0]=make_float4(gcp[0],gcp[1],gcp[2],gcp[3]);
  gdst[1]=make_float4(gcp[4],gcp[5],gcp[6],gcp[7]);
  gdst[2]=make_float4(gcp[8],gcp[9],gcp[10],gcp[11]);
  gdst[3]=make_float4(gcp[12],gcp[13],gcp[14],0.f);
  ws[OFF_PN2+idx] = pn2; ws[OFF_GN2+idx] = gn2;

  // per-idx min-state init (k_pair runs strictly after)
  ((unsigned*)ws)[OFF_BEST + idx] = 0x7F800000u;   // +inf
  ((unsigned*)ws)[OFF_PK   + idx] = 0xFFFFFFFFu;

  // ---- cheap per-point losses -> per-block partials ----
  const float cosd = 1.f - (dl0*gd0 + dl1*gd1 + dl2*gd2);
  const float proj = gd0*al0 + gd1*al1 + gd2*al2;
  const float o0 = al0 - proj*gd0, o1 = al1 - proj*gd1, o2 = al2 - proj*gd2;
  const float on = sqrtf(o0*o0 + o1*o1 + o2*o2);
  const float inv = 1.f / fmaxf(on, 1e-12f);
  const float cosa = 1.f - inv*(o0*ad0 + o1*ad1 + o2*ad2);

  float offv = 0.f;
  #pragma unroll
  for (int k = 0; k < NBn; k++) {
    const float x = goff[idx*NBn+k], lab = olab[idx*NBn+k];
    const float bce = lab * sp_(-x) + (1.f - lab) * sp_(x);
    offv = fmaf(binw[k], bce, offv);
  }
  offv *= (1.0f / NBn);
  const float sb = bsh[idx];
  const float sbce = sc * sp_(-sb) + (1.f - sc) * sp_(sb);

  float* part = ws + OFF_PART + (size_t)pb*8;
  float t;
  t = blockSum_(cosd*sc, red); if (threadIdx.x == 0) part[0] = t;
  t = blockSum_(cosa*sc, red); if (threadIdx.x == 0) part[1] = t;
  t = blockSum_(offv*sc, red); if (threadIdx.x == 0) part[2] = t;
  t = blockSum_(sc, red);      if (threadIdx.x == 0) part[3] = t;
  t = blockSum_(sbce, red);    if (threadIdx.x == 0) part[4] = t;
}

// ---------- single-pass pairwise kernel. grid (Nn/TCOLS, Nn/NCH, Bn) = (8,32,4), block 256.
// Each lane owns 4 gt columns in registers. Sym distances via the permutation identity
// (sym = gt with pts 2<->3 swapped): dot_sym = dot_gt + (p[6..8]-p[9..11]).(g[9..11]-g[6..8]).
// Pred rows staged in LDS, read per-j at wave-uniform addresses (broadcast ds_read_b128).
// Forward row-min uses the DPP reduction (VALU pipe) — no shfl/DS butterfly.
// __launch_bounds__(256, 2): VGPR cap 256 — the kernel needs ~135 live VGPRs; the
// round-8 (256,4) bound capped it at 128-and-spilled (112 MB scratch writes/dispatch).
__global__ __launch_bounds__(256, 2) void k_pair(const float* __restrict__ succ,
                                                 float* __restrict__ ws) {
  __shared__ float pls[NCH*16];       // 64 pred rows x 16 floats
  __shared__ float pn2s[NCH];
  __shared__ unsigned bkey[TCOLS];
  const int tile = blockIdx.x * TCOLS, b = blockIdx.z;
  const int bN = b * Nn;
  const int ny0 = blockIdx.y * NCH;
  const int tid = threadIdx.x;
  const int lane = tid & 63;
  const int wid = __builtin_amdgcn_readfirstlane(tid >> 6);

  // stage pred rows: 256 threads x 1 float4 = 64 rows x 16 floats
  {
    const int row = tid >> 2, q = tid & 3;
    ((float4*)pls)[tid] = ((const float4*)(ws + OFF_PRED))[(size_t)(bN + ny0 + row)*4 + q];
    if (tid < NCH) pn2s[tid] = ws[OFF_PN2 + bN + ny0 + tid];
    bkey[tid] = 0xFFFFFFFFu;
  }

  // lane's four columns (registers)
  float4 gq[4][4];
  float  gnc[4], biasc[4], ex[4], ey[4], ez[4];
  unsigned kk[4];
  const float4* G = (const float4*)(ws + OFF_GT);
  #pragma unroll
  for (int c = 0; c < 4; c++) {
    const int r = bN + tile + c*64 + lane;
    gq[c][0] = G[(size_t)r*4+0]; gq[c][1] = G[(size_t)r*4+1];
    gq[c][2] = G[(size_t)r*4+2]; gq[c][3] = G[(size_t)r*4+3];
    gnc[c]   = ws[OFF_GN2 + r];
    biasc[c] = (succ[r] != 0.f) ? 0.f : BIGM;
    // sym-delta fragments: g[9..11] - g[6..8]
    ex[c] = gq[c][2].y - gq[c][1].z;
    ey[c] = gq[c][2].z - gq[c][1].w;
    ez[c] = gq[c][2].w - gq[c][2].x;
    kk[c] = 0xFFFFFFFFu;
  }

  float f[16];
  __syncthreads();

  const float4* PL = (const float4*)pls + (size_t)wid*16*4;   // this wave's 16 rows

  #pragma unroll
  for (int j = 0; j < 16; j++) {
    const float4 p0 = PL[j*4+0], p1 = PL[j*4+1], p2 = PL[j*4+2], p3 = PL[j*4+3];
    const float pn2 = pn2s[wid*16 + j];
    const float pd0 = p1.z - p2.y, pd1 = p1.w - p2.z, pd2 = p2.x - p2.w;
    const unsigned nl = (unsigned)(ny0 + wid*16 + j), nh = nl | 0x800u;

    float fj = BIGM * 2.f;
    #pragma unroll
    for (int c = 0; c < 4; c++) {
      float s;
      s = fmaf(p0.w, gq[c][0].w, fmaf(p0.z, gq[c][0].z, fmaf(p0.y, gq[c][0].y, p0.x*gq[c][0].x)));
      s = fmaf(p1.w, gq[c][1].w, fmaf(p1.z, gq[c][1].z, fmaf(p1.y, gq[c][1].y, fmaf(p1.x, gq[c][1].x, s))));
      s = fmaf(p2.w, gq[c][2].w, fmaf(p2.z, gq[c][2].z, fmaf(p2.y, gq[c][2].y, fmaf(p2.x, gq[c][2].x, s))));
      const float dot = fmaf(p3.z, gq[c][3].z, fmaf(p3.y, gq[c][3].y, fmaf(p3.x, gq[c][3].x, s)));
      const float del = fmaf(pd0, ex[c], fmaf(pd1, ey[c], pd2*ez[c]));
      const float q1  = fmaf(-2.f, dot, pn2 + gnc[c]);
      const float d1  = fmaxf(q1, 0.f);
      const float d2  = fmaxf(fmaf(-2.f, del, q1), 0.f);

      // backward packed key: (dist&0xFFFFF000)|(mat<<11)|n — u32 min is lexicographic
      // (d, mat, n): d-tie -> mat0 (= reference i1-on-tie), then first n.
      kk[c] = min(kk[c], min((__float_as_uint(d1) & 0xFFFFF000u) | nl,
                             (__float_as_uint(d2) & 0xFFFFF000u) | nh));

      fj = fminf(fj, fminf(d1, d2) + biasc[c]);
    }
    f[j] = fj;
  }

  // forward: 16 independent DPP wave-min chains (VALU pipe); lane 63 owns results
  #pragma unroll
  for (int j = 0; j < 16; j++) f[j] = waveMin_(f[j]);
  if (lane == 63) {
    #pragma unroll
    for (int j = 0; j < 16; j++)
      atomicMin((unsigned*)ws + OFF_BEST + bN + ny0 + wid*16 + j, __float_as_uint(f[j]));
  }

  // merge the 4 waves' backward keys (same columns, disjoint n) then one global atomic/col
  #pragma unroll
  for (int c = 0; c < 4; c++) atomicMin(&bkey[c*64 + lane], kk[c]);
  __syncthreads();
  atomicMin((unsigned*)ws + OFF_PK + bN + tile + tid, bkey[tid]);
}

// ---------- reduce: adds/g2p per-block partials. grid (Nn/256, Bn) = (8,4), block 256.
__global__ __launch_bounds__(256) void k_red(const float* __restrict__ bsp,
                                             const float* __restrict__ succ,
                                             float* __restrict__ ws) {
  __shared__ float red[4];
  const int b = blockIdx.y, nt = blockIdx.x;
  const int idx = b*Nn + nt*256 + threadIdx.x;

  const float best = __uint_as_float(((const unsigned*)ws)[OFF_BEST + idx]);
  const float adds = (best < 1e30f) ? bsp[idx] * sqrtf(best) : 0.f;  // >=1e30 <=> no positives -> gate 0

  const unsigned key = ((const unsigned*)ws)[OFF_PK + idx];
  const float d = __uint_as_float(key & 0xFFFFF000u);
  const int  id = (int)(key & 0x7FFu);
  const float g2p = bsp[b*Nn + id] * d * succ[idx];

  float* part = ws + OFF_PART + (size_t)(b*8 + nt)*8;
  float t;
  t = blockSum_(adds, red); if (threadIdx.x == 0) part[5] = t;
  t = blockSum_(g2p, red);  if (threadIdx.x == 0) part[6] = t;
}

// ---------- finalize: 1 block, 64 threads, wave-only reduction of 32x7 partials
__global__ __launch_bounds__(64) void k_fin(const float* __restrict__ ws, float* __restrict__ out) {
  const int t = threadIdx.x;
  float v[7];
  #pragma unroll
  for (int c = 0; c < 7; c++) v[c] = (t < 32) ? ws[OFF_PART + t*8 + c] : 0.f;
  #pragma unroll
  for (int o = 1; o < 8; o <<= 1) {
    #pragma unroll
    for (int c = 0; c < 7; c++) v[c] += __shfl_xor(v[c], o, 64);
  }
  // each 8-lane group (t<32) now holds per-b sums (b = t>>3)
  const float pos = fmaxf(v[3], 1.f);
  float vb   = (v[0] + v[1] + v[2] + v[6]) / pos;   // dir + app + off + g2p, per-b normalized
  float bce  = v[4];
  float adds = v[5];
  #pragma unroll
  for (int o = 8; o < 32; o <<= 1) {
    vb   += __shfl_xor(vb,   o, 64);
    bce  += __shfl_xor(bce,  o, 64);
    adds += __shfl_xor(adds, o, 64);
  }
  if (t == 0)
    out[0] = vb * 0.25f + bce * (1.f/BN) + 10.f * adds * (1.f/BN);
}

extern "C" void kernel_launch(void* const* d_in, const int* in_sizes, int n_in,
                              void* d_out, int out_size, void* d_ws, size_t ws_size,
                              hipStream_t stream) {
  const float* gdir  = (const float*)d_in[0];
  const float* adirp = (const float*)d_in[1];
  const float* goff  = (const float*)d_in[2];
  const float* ppts  = (const float*)d_in[3];
  const float* bsp   = (const float*)d_in[4];
  const float* bsh   = (const float*)d_in[5];
  const float* dlab  = (const float*)d_in[6];
  const float* olab  = (const float*)d_in[7];
  const float* succ  = (const float*)d_in[8];
  const float* alab  = (const float*)d_in[9];
  const float* binv  = (const float*)d_in[10];
  const float* binw  = (const float*)d_in[11];
  const float* cpts  = (const float*)d_in[12];
  const float* scpts = (const float*)d_in[13];
  float* ws  = (float*)d_ws;
  float* out = (float*)d_out;
  (void)scpts;

  k_prep<<<dim3(BN/256), dim3(256), 0, stream>>>(gdir, adirp, goff, ppts, bsh,
                                                 dlab, olab, succ, alab,
                                                 binv, binw, cpts, scpts, ws);
  k_pair<<<dim3(Nn/TCOLS, Nn/NCH, Bn), dim3(256), 0, stream>>>(succ, ws);
  k_red<<<dim3(Nn/256, Bn), dim3(256), 0, stream>>>(bsp, succ, ws);
  k_fin<<<1, 64, 0, stream>>>(ws, out);
}

// Round 10
// 114.892 us; speedup vs baseline: 1.2287x; 1.0139x over previous
//
#include <hip/hip_runtime.h>

#define Bn 4
#define Nn 2048
#define NBn 10
#define BN (Bn*Nn)
#define TCOLS 256     // gt columns per block (4 per lane, shared by all 4 waves)
#define NCH 128       // pred rows per block (32 per wave, two 16-row passes)
#define BIGM 1e32f

// ws layout in float (4-byte) units  (sym cloud eliminated: it's gt with pts 2<->3 swapped)
#define OFF_PRED 0
#define OFF_GT   (BN*16)
#define OFF_PN2  (2*BN*16)
#define OFF_GN2  (OFF_PN2 + BN)
#define OFF_BEST (OFF_GN2 + BN)      // u32 per (b,n): forward min dist (fp32 bits)
#define OFF_PK   (OFF_BEST + BN)     // u32 per (b,m): (dist&0xFFFFF000)|(mat<<11)|n
#define OFF_PART (OFF_PK + BN)       // 32 records x 8 floats: 0=dir 1=app 2=off 3=pos 4=bce 5=adds 6=g2p
#define OFF_CNT  (OFF_PART + 32*8)   // completion counter for last-block finalize

__device__ inline float sp_(float x) {            // jax.nn.softplus, stable form
  return fmaxf(x, 0.0f) + log1pf(expf(-fabsf(x)));
}

// wave64 min-reduce on the VALU pipe (DPP), no DS ops. Result valid in lane 63.
__device__ inline float waveMin_(float v) {
  const int INFI = 0x7F800000;
#define DPPMIN(ctrl) \
  v = fminf(v, __int_as_float(__builtin_amdgcn_update_dpp(INFI, __float_as_int(v), ctrl, 0xf, 0xf, false)))
  DPPMIN(0x111);  // row_shr:1
  DPPMIN(0x112);  // row_shr:2
  DPPMIN(0x114);  // row_shr:4
  DPPMIN(0x118);  // row_shr:8   -> lane15 of each row16 holds row min
  DPPMIN(0x142);  // row_bcast:15
  DPPMIN(0x143);  // row_bcast:31 -> lane63 holds wave min
#undef DPPMIN
  return v;
}

__device__ inline float blockSum_(float v, float* red) {
  #pragma unroll
  for (int o = 32; o > 0; o >>= 1) v += __shfl_down(v, o, 64);
  __syncthreads();
  if ((threadIdx.x & 63) == 0) red[threadIdx.x >> 6] = v;
  __syncthreads();
  return red[0] + red[1] + red[2] + red[3];
}

// ---------- prep: frames, control points, norms, min-state init, cheap per-point
// loss partials. grid (BN/256) = 32, block 256.
__global__ __launch_bounds__(256) void k_prep(
    const float* __restrict__ gdir, const float* __restrict__ adirp,
    const float* __restrict__ goff, const float* __restrict__ ppts,
    const float* __restrict__ bsh,
    const float* __restrict__ dlab, const float* __restrict__ olab,
    const float* __restrict__ succ, const float* __restrict__ alab,
    const float* __restrict__ binv, const float* __restrict__ binw,
    const float* __restrict__ cpts, const float* __restrict__ scpts,
    float* __restrict__ ws)
{
  __shared__ float red[4];
  const int pb = blockIdx.x;
  const int idx = pb * 256 + threadIdx.x;

  const float gd0=gdir[idx*3+0],  gd1=gdir[idx*3+1],  gd2=gdir[idx*3+2];
  const float ad0=adirp[idx*3+0], ad1=adirp[idx*3+1], ad2=adirp[idx*3+2];
  const float dl0=dlab[idx*3+0],  dl1=dlab[idx*3+1],  dl2=dlab[idx*3+2];
  const float al0=alab[idx*3+0],  al1=alab[idx*3+1],  al2=alab[idx*3+2];
  const float pt0=ppts[idx*3+0],  pt1=ppts[idx*3+1],  pt2=ppts[idx*3+2];
  const float sc = succ[idx];

  // argmax (first occurrence, matches jnp.argmax)
  float bv = goff[idx*NBn]; int ap = 0;
  #pragma unroll
  for (int k = 1; k < NBn; k++) { float v = goff[idx*NBn+k]; if (v > bv) { bv = v; ap = k; } }
  float bg = olab[idx*NBn]; int ag = 0;
  #pragma unroll
  for (int k = 1; k < NBn; k++) { float v = olab[idx*NBn+k]; if (v > bg) { bg = v; ag = k; } }
  const float tp = binv[ap] * 0.5f;
  const float tg = binv[ag] * 0.5f;

  // frames: cross = cross(approach, base); t = pt + 0.5*thickness*base
  const float cp0 = ad1*gd2 - ad2*gd1, cp1 = ad2*gd0 - ad0*gd2, cp2 = ad0*gd1 - ad1*gd0;
  const float cg0 = al1*dl2 - al2*dl1, cg1 = al2*dl0 - al0*dl2, cg2 = al0*dl1 - al1*dl0;
  const float tpx = pt0 + tp*gd0, tpy = pt1 + tp*gd1, tpz = pt2 + tp*gd2;
  const float tgx = pt0 + tg*dl0, tgy = pt1 + tg*dl1, tgz = pt2 + tg*dl2;

  float pcp[15], gcp[15];
  float pn2 = 0.f, gn2 = 0.f;
  #pragma unroll
  for (int p = 0; p < 5; p++) {
    const float cx = cpts[p*3], cy = cpts[p*3+1], cz = cpts[p*3+2];
    float x, y, z;
    x = gd0*cx + cp0*cy + ad0*cz + tpx;
    y = gd1*cx + cp1*cy + ad1*cz + tpy;
    z = gd2*cx + cp2*cy + ad2*cz + tpz;
    pcp[p*3+0]=x; pcp[p*3+1]=y; pcp[p*3+2]=z;
    pn2 = fmaf(x,x, fmaf(y,y, fmaf(z,z, pn2)));
    x = dl0*cx + cg0*cy + al0*cz + tgx;
    y = dl1*cx + cg1*cy + al1*cz + tgy;
    z = dl2*cx + cg2*cy + al2*cz + tgz;
    gcp[p*3+0]=x; gcp[p*3+1]=y; gcp[p*3+2]=z;
    gn2 = fmaf(x,x, fmaf(y,y, fmaf(z,z, gn2)));
  }

  float4* pd = (float4*)(ws + OFF_PRED) + (size_t)idx*4;
  pd[0]=make_float4(pcp[0],pcp[1],pcp[2],pcp[3]);
  pd[1]=make_float4(pcp[4],pcp[5],pcp[6],pcp[7]);
  pd[2]=make_float4(pcp[8],pcp[9],pcp[10],pcp[11]);
  pd[3]=make_float4(pcp[12],pcp[13],pcp[14],0.f);
  float4* gdst = (float4*)(ws + OFF_GT) + (size_t)idx*4;
  gdst[0]=make_float4(gcp[0],gcp[1],gcp[2],gcp[3]);
  gdst[1]=make_float4(gcp[4],gcp[5],gcp[6],gcp[7]);
  gdst[2]=make_float4(gcp[8],gcp[9],gcp[10],gcp[11]);
  gdst[3]=make_float4(gcp[12],gcp[13],gcp[14],0.f);
  ws[OFF_PN2+idx] = pn2; ws[OFF_GN2+idx] = gn2;

  // per-idx min-state init (k_pair runs strictly after); idx 0 zeroes the counter
  ((unsigned*)ws)[OFF_BEST + idx] = 0x7F800000u;   // +inf
  ((unsigned*)ws)[OFF_PK   + idx] = 0xFFFFFFFFu;
  if (idx == 0) ((unsigned*)ws)[OFF_CNT] = 0u;

  // ---- cheap per-point losses -> per-block partials ----
  const float cosd = 1.f - (dl0*gd0 + dl1*gd1 + dl2*gd2);
  const float proj = gd0*al0 + gd1*al1 + gd2*al2;
  const float o0 = al0 - proj*gd0, o1 = al1 - proj*gd1, o2 = al2 - proj*gd2;
  const float on = sqrtf(o0*o0 + o1*o1 + o2*o2);
  const float inv = 1.f / fmaxf(on, 1e-12f);
  const float cosa = 1.f - inv*(o0*ad0 + o1*ad1 + o2*ad2);

  float offv = 0.f;
  #pragma unroll
  for (int k = 0; k < NBn; k++) {
    const float x = goff[idx*NBn+k], lab = olab[idx*NBn+k];
    const float bce = lab * sp_(-x) + (1.f - lab) * sp_(x);
    offv = fmaf(binw[k], bce, offv);
  }
  offv *= (1.0f / NBn);
  const float sb = bsh[idx];
  const float sbce = sc * sp_(-sb) + (1.f - sc) * sp_(sb);

  float* part = ws + OFF_PART + (size_t)pb*8;
  float t;
  t = blockSum_(cosd*sc, red); if (threadIdx.x == 0) part[0] = t;
  t = blockSum_(cosa*sc, red); if (threadIdx.x == 0) part[1] = t;
  t = blockSum_(offv*sc, red); if (threadIdx.x == 0) part[2] = t;
  t = blockSum_(sc, red);      if (threadIdx.x == 0) part[3] = t;
  t = blockSum_(sbce, red);    if (threadIdx.x == 0) part[4] = t;
}

// ---------- single-pass pairwise kernel. grid (Nn/TCOLS, Nn/NCH, Bn) = (8,16,4), block 256.
// Each lane owns 4 gt columns in registers. Sym distances via the permutation identity
// (sym = gt with pts 2<->3 swapped): dot_sym = dot_gt + (p[6..8]-p[9..11]).(g[9..11]-g[6..8]).
// 128 pred rows staged in LDS; each wave handles 32 rows in two 16-row passes (f[16]
// reused). Forward row-min via DPP (VALU pipe). __launch_bounds__(256,2) -> no spill.
__global__ __launch_bounds__(256, 2) void k_pair(const float* __restrict__ succ,
                                                 float* __restrict__ ws) {
  __shared__ float pls[NCH*16];       // 128 pred rows x 16 floats
  __shared__ float pn2s[NCH];
  __shared__ unsigned bkey[TCOLS];
  const int tile = blockIdx.x * TCOLS, b = blockIdx.z;
  const int bN = b * Nn;
  const int ny0 = blockIdx.y * NCH;
  const int tid = threadIdx.x;
  const int lane = tid & 63;
  const int wid = __builtin_amdgcn_readfirstlane(tid >> 6);

  // stage pred rows: 512 float4s by 256 threads (2 each)
  {
    #pragma unroll
    for (int e = 0; e < 2; e++) {
      const int ent = e*256 + tid;
      const int row = ent >> 2, q = ent & 3;
      ((float4*)pls)[ent] = ((const float4*)(ws + OFF_PRED))[(size_t)(bN + ny0 + row)*4 + q];
    }
    if (tid < NCH) pn2s[tid] = ws[OFF_PN2 + bN + ny0 + tid];
    bkey[tid] = 0xFFFFFFFFu;
  }

  // lane's four columns (registers)
  float4 gq[4][4];
  float  gnc[4], biasc[4], ex[4], ey[4], ez[4];
  unsigned kk[4];
  const float4* G = (const float4*)(ws + OFF_GT);
  #pragma unroll
  for (int c = 0; c < 4; c++) {
    const int r = bN + tile + c*64 + lane;
    gq[c][0] = G[(size_t)r*4+0]; gq[c][1] = G[(size_t)r*4+1];
    gq[c][2] = G[(size_t)r*4+2]; gq[c][3] = G[(size_t)r*4+3];
    gnc[c]   = ws[OFF_GN2 + r];
    biasc[c] = (succ[r] != 0.f) ? 0.f : BIGM;
    // sym-delta fragments: g[9..11] - g[6..8]
    ex[c] = gq[c][2].y - gq[c][1].z;
    ey[c] = gq[c][2].z - gq[c][1].w;
    ez[c] = gq[c][2].w - gq[c][2].x;
    kk[c] = 0xFFFFFFFFu;
  }
  __syncthreads();

  for (int p = 0; p < 2; p++) {                  // two 16-row passes per wave
    const int rbase = wid*32 + p*16;
    const float4* PL = (const float4*)pls + (size_t)rbase*4;
    float f[16];

    #pragma unroll
    for (int j = 0; j < 16; j++) {
      const float4 p0 = PL[j*4+0], p1 = PL[j*4+1], p2 = PL[j*4+2], p3 = PL[j*4+3];
      const float pn2 = pn2s[rbase + j];
      const float pd0 = p1.z - p2.y, pd1 = p1.w - p2.z, pd2 = p2.x - p2.w;
      const unsigned nl = (unsigned)(ny0 + rbase + j), nh = nl | 0x800u;

      float fj = BIGM * 2.f;
      #pragma unroll
      for (int c = 0; c < 4; c++) {
        float s;
        s = fmaf(p0.w, gq[c][0].w, fmaf(p0.z, gq[c][0].z, fmaf(p0.y, gq[c][0].y, p0.x*gq[c][0].x)));
        s = fmaf(p1.w, gq[c][1].w, fmaf(p1.z, gq[c][1].z, fmaf(p1.y, gq[c][1].y, fmaf(p1.x, gq[c][1].x, s))));
        s = fmaf(p2.w, gq[c][2].w, fmaf(p2.z, gq[c][2].z, fmaf(p2.y, gq[c][2].y, fmaf(p2.x, gq[c][2].x, s))));
        const float dot = fmaf(p3.z, gq[c][3].z, fmaf(p3.y, gq[c][3].y, fmaf(p3.x, gq[c][3].x, s)));
        const float del = fmaf(pd0, ex[c], fmaf(pd1, ey[c], pd2*ez[c]));
        const float q1  = fmaf(-2.f, dot, pn2 + gnc[c]);
        const float d1  = fmaxf(q1, 0.f);
        const float d2  = fmaxf(fmaf(-2.f, del, q1), 0.f);

        // backward packed key: (dist&0xFFFFF000)|(mat<<11)|n — u32 min is lexicographic
        // (d, mat, n): d-tie -> mat0 (= reference i1-on-tie), then first n.
        kk[c] = min(kk[c], min((__float_as_uint(d1) & 0xFFFFF000u) | nl,
                               (__float_as_uint(d2) & 0xFFFFF000u) | nh));

        fj = fminf(fj, fminf(d1, d2) + biasc[c]);
      }
      f[j] = fj;
    }

    // forward: 16 independent DPP wave-min chains (VALU pipe); lane 63 owns results
    #pragma unroll
    for (int j = 0; j < 16; j++) f[j] = waveMin_(f[j]);
    if (lane == 63) {
      #pragma unroll
      for (int j = 0; j < 16; j++)
        atomicMin((unsigned*)ws + OFF_BEST + bN + ny0 + rbase + j, __float_as_uint(f[j]));
    }
  }

  // merge the 4 waves' backward keys (same columns, disjoint n) then one global atomic/col
  #pragma unroll
  for (int c = 0; c < 4; c++) atomicMin(&bkey[c*64 + lane], kk[c]);
  __syncthreads();
  atomicMin((unsigned*)ws + OFF_PK + bN + tile + tid, bkey[tid]);
}

// ---------- fused reduce+finalize. grid (Nn/256, Bn) = (8,4), block 256.
// Each block writes its adds/g2p partials; the LAST block (device atomic counter)
// performs the 32-record final combine and writes out[0].
__global__ __launch_bounds__(256) void k_redfin(const float* __restrict__ bsp,
                                                const float* __restrict__ succ,
                                                float* __restrict__ ws,
                                                float* __restrict__ out) {
  __shared__ float red[4];
  __shared__ int isLast;
  const int b = blockIdx.y, nt = blockIdx.x;
  const int idx = b*Nn + nt*256 + threadIdx.x;

  const float best = __uint_as_float(((const unsigned*)ws)[OFF_BEST + idx]);
  const float adds = (best < 1e30f) ? bsp[idx] * sqrtf(best) : 0.f;  // >=1e30 <=> no positives -> gate 0

  const unsigned key = ((const unsigned*)ws)[OFF_PK + idx];
  const float d = __uint_as_float(key & 0xFFFFF000u);
  const int  id = (int)(key & 0x7FFu);
  const float g2p = bsp[b*Nn + id] * d * succ[idx];

  float* part = ws + OFF_PART + (size_t)(b*8 + nt)*8;
  float t;
  t = blockSum_(adds, red); if (threadIdx.x == 0) part[5] = t;
  t = blockSum_(g2p, red);  if (threadIdx.x == 0) part[6] = t;

  // completion protocol: release fence -> count; last block acquires and finalizes
  __threadfence();
  if (threadIdx.x == 0)
    isLast = (atomicAdd((unsigned*)ws + OFF_CNT, 1u) == 31u);
  __syncthreads();
  if (!isLast) return;
  __threadfence();

  const int tt = threadIdx.x;
  if (tt >= 64) return;
  float v[7];
  #pragma unroll
  for (int c = 0; c < 7; c++) v[c] = (tt < 32) ? ws[OFF_PART + tt*8 + c] : 0.f;
  #pragma unroll
  for (int o = 1; o < 8; o <<= 1) {
    #pragma unroll
    for (int c = 0; c < 7; c++) v[c] += __shfl_xor(v[c], o, 64);
  }
  // each 8-lane group (tt<32) now holds per-b sums (b = tt>>3)
  const float pos = fmaxf(v[3], 1.f);
  float vb   = (v[0] + v[1] + v[2] + v[6]) / pos;   // dir + app + off + g2p, per-b normalized
  float bce  = v[4];
  float adds2 = v[5];
  #pragma unroll
  for (int o = 8; o < 32; o <<= 1) {
    vb    += __shfl_xor(vb,    o, 64);
    bce   += __shfl_xor(bce,   o, 64);
    adds2 += __shfl_xor(adds2, o, 64);
  }
  if (tt == 0)
    out[0] = vb * 0.25f + bce * (1.f/BN) + 10.f * adds2 * (1.f/BN);
}

extern "C" void kernel_launch(void* const* d_in, const int* in_sizes, int n_in,
                              void* d_out, int out_size, void* d_ws, size_t ws_size,
                              hipStream_t stream) {
  const float* gdir  = (const float*)d_in[0];
  const float* adirp = (const float*)d_in[1];
  const float* goff  = (const float*)d_in[2];
  const float* ppts  = (const float*)d_in[3];
  const float* bsp   = (const float*)d_in[4];
  const float* bsh   = (const float*)d_in[5];
  const float* dlab  = (const float*)d_in[6];
  const float* olab  = (const float*)d_in[7];
  const float* succ  = (const float*)d_in[8];
  const float* alab  = (const float*)d_in[9];
  const float* binv  = (const float*)d_in[10];
  const float* binw  = (const float*)d_in[11];
  const float* cpts  = (const float*)d_in[12];
  const float* scpts = (const float*)d_in[13];
  float* ws  = (float*)d_ws;
  float* out = (float*)d_out;
  (void)scpts;

  k_prep<<<dim3(BN/256), dim3(256), 0, stream>>>(gdir, adirp, goff, ppts, bsh,
                                                 dlab, olab, succ, alab,
                                                 binv, binw, cpts, scpts, ws);
  k_pair<<<dim3(Nn/TCOLS, Nn/NCH, Bn), dim3(256), 0, stream>>>(succ, ws);
  k_redfin<<<dim3(Nn/256, Bn), dim3(256), 0, stream>>>(bsp, succ, ws, out);
}

// Round 11
// 113.261 us; speedup vs baseline: 1.2464x; 1.0144x over previous
//
#include <hip/hip_runtime.h>

#define Bn 4
#define Nn 2048
#define NBn 10
#define BN (Bn*Nn)
#define TCOLS 256     // gt columns per block (4 per lane, shared by all 4 waves)
#define NCH 128       // pred rows per block (32 per wave, two 16-row passes)
#define BIGM 1e32f

// ws layout in float (4-byte) units  (sym cloud eliminated: it's gt with pts 2<->3 swapped)
// cloud rows are 16 floats: [15 coords][norm2 in slot 15]
#define OFF_PRED 0
#define OFF_GT   (BN*16)
#define OFF_BEST (2*BN*16)           // u32 per (b,n): forward min dist (fp32 bits)
#define OFF_PK   (OFF_BEST + BN)     // u32 per (b,m): (dist&0xFFFFF000)|(mat<<11)|n
#define OFF_PART (OFF_PK + BN)       // 64 records x 8: 0=dir 1=app 2=off 3=pos 4=bce 5=adds 6=g2p
#define OFF_CNT  (OFF_PART + 64*8)   // completion counter for last-block finalize

__device__ inline float sp_(float x) {            // jax.nn.softplus, stable form
  return fmaxf(x, 0.0f) + log1pf(expf(-fabsf(x)));
}

// wave64 min-reduce on the VALU pipe (DPP), no DS ops. Result valid in lane 63.
__device__ inline float waveMin_(float v) {
  const int INFI = 0x7F800000;
#define DPPMIN(ctrl) \
  v = fminf(v, __int_as_float(__builtin_amdgcn_update_dpp(INFI, __float_as_int(v), ctrl, 0xf, 0xf, false)))
  DPPMIN(0x111);  // row_shr:1
  DPPMIN(0x112);  // row_shr:2
  DPPMIN(0x114);  // row_shr:4
  DPPMIN(0x118);  // row_shr:8   -> lane15 of each row16 holds row min
  DPPMIN(0x142);  // row_bcast:15
  DPPMIN(0x143);  // row_bcast:31 -> lane63 holds wave min
#undef DPPMIN
  return v;
}

// block sum for 128-thread blocks (2 waves)
__device__ inline float blockSum128_(float v, float* red) {
  #pragma unroll
  for (int o = 32; o > 0; o >>= 1) v += __shfl_down(v, o, 64);
  __syncthreads();
  if ((threadIdx.x & 63) == 0) red[threadIdx.x >> 6] = v;
  __syncthreads();
  return red[0] + red[1];
}

// ---------- prep: frames, control points, norms, min-state init, cheap per-point
// loss partials. grid (BN/128) = 64, block 128.
__global__ __launch_bounds__(128) void k_prep(
    const float* __restrict__ gdir, const float* __restrict__ adirp,
    const float* __restrict__ goff, const float* __restrict__ ppts,
    const float* __restrict__ bsh,
    const float* __restrict__ dlab, const float* __restrict__ olab,
    const float* __restrict__ succ, const float* __restrict__ alab,
    const float* __restrict__ binv, const float* __restrict__ binw,
    const float* __restrict__ cpts, const float* __restrict__ scpts,
    float* __restrict__ ws)
{
  __shared__ float red[2];
  const int pb = blockIdx.x;
  const int idx = pb * 128 + threadIdx.x;

  const float gd0=gdir[idx*3+0],  gd1=gdir[idx*3+1],  gd2=gdir[idx*3+2];
  const float ad0=adirp[idx*3+0], ad1=adirp[idx*3+1], ad2=adirp[idx*3+2];
  const float dl0=dlab[idx*3+0],  dl1=dlab[idx*3+1],  dl2=dlab[idx*3+2];
  const float al0=alab[idx*3+0],  al1=alab[idx*3+1],  al2=alab[idx*3+2];
  const float pt0=ppts[idx*3+0],  pt1=ppts[idx*3+1],  pt2=ppts[idx*3+2];
  const float sc = succ[idx];

  // argmax (first occurrence, matches jnp.argmax)
  float bv = goff[idx*NBn]; int ap = 0;
  #pragma unroll
  for (int k = 1; k < NBn; k++) { float v = goff[idx*NBn+k]; if (v > bv) { bv = v; ap = k; } }
  float bg = olab[idx*NBn]; int ag = 0;
  #pragma unroll
  for (int k = 1; k < NBn; k++) { float v = olab[idx*NBn+k]; if (v > bg) { bg = v; ag = k; } }
  const float tp = binv[ap] * 0.5f;
  const float tg = binv[ag] * 0.5f;

  // frames: cross = cross(approach, base); t = pt + 0.5*thickness*base
  const float cp0 = ad1*gd2 - ad2*gd1, cp1 = ad2*gd0 - ad0*gd2, cp2 = ad0*gd1 - ad1*gd0;
  const float cg0 = al1*dl2 - al2*dl1, cg1 = al2*dl0 - al0*dl2, cg2 = al0*dl1 - al1*dl0;
  const float tpx = pt0 + tp*gd0, tpy = pt1 + tp*gd1, tpz = pt2 + tp*gd2;
  const float tgx = pt0 + tg*dl0, tgy = pt1 + tg*dl1, tgz = pt2 + tg*dl2;

  float pcp[15], gcp[15];
  float pn2 = 0.f, gn2 = 0.f;
  #pragma unroll
  for (int p = 0; p < 5; p++) {
    const float cx = cpts[p*3], cy = cpts[p*3+1], cz = cpts[p*3+2];
    float x, y, z;
    x = gd0*cx + cp0*cy + ad0*cz + tpx;
    y = gd1*cx + cp1*cy + ad1*cz + tpy;
    z = gd2*cx + cp2*cy + ad2*cz + tpz;
    pcp[p*3+0]=x; pcp[p*3+1]=y; pcp[p*3+2]=z;
    pn2 = fmaf(x,x, fmaf(y,y, fmaf(z,z, pn2)));
    x = dl0*cx + cg0*cy + al0*cz + tgx;
    y = dl1*cx + cg1*cy + al1*cz + tgy;
    z = dl2*cx + cg2*cy + al2*cz + tgz;
    gcp[p*3+0]=x; gcp[p*3+1]=y; gcp[p*3+2]=z;
    gn2 = fmaf(x,x, fmaf(y,y, fmaf(z,z, gn2)));
  }

  // norms packed into slot 15 of each 16-float row
  float4* pd = (float4*)(ws + OFF_PRED) + (size_t)idx*4;
  pd[0]=make_float4(pcp[0],pcp[1],pcp[2],pcp[3]);
  pd[1]=make_float4(pcp[4],pcp[5],pcp[6],pcp[7]);
  pd[2]=make_float4(pcp[8],pcp[9],pcp[10],pcp[11]);
  pd[3]=make_float4(pcp[12],pcp[13],pcp[14],pn2);
  float4* gdst = (float4*)(ws + OFF_GT) + (size_t)idx*4;
  gdst[0]=make_float4(gcp[0],gcp[1],gcp[2],gcp[3]);
  gdst[1]=make_float4(gcp[4],gcp[5],gcp[6],gcp[7]);
  gdst[2]=make_float4(gcp[8],gcp[9],gcp[10],gcp[11]);
  gdst[3]=make_float4(gcp[12],gcp[13],gcp[14],gn2);

  // per-idx min-state init (k_pair runs strictly after); idx 0 zeroes the counter
  ((unsigned*)ws)[OFF_BEST + idx] = 0x7F800000u;   // +inf
  ((unsigned*)ws)[OFF_PK   + idx] = 0xFFFFFFFFu;
  if (idx == 0) ((unsigned*)ws)[OFF_CNT] = 0u;

  // ---- cheap per-point losses -> per-block partials (record pb, fields 0..4) ----
  const float cosd = 1.f - (dl0*gd0 + dl1*gd1 + dl2*gd2);
  const float proj = gd0*al0 + gd1*al1 + gd2*al2;
  const float o0 = al0 - proj*gd0, o1 = al1 - proj*gd1, o2 = al2 - proj*gd2;
  const float on = sqrtf(o0*o0 + o1*o1 + o2*o2);
  const float inv = 1.f / fmaxf(on, 1e-12f);
  const float cosa = 1.f - inv*(o0*ad0 + o1*ad1 + o2*ad2);

  float offv = 0.f;
  #pragma unroll
  for (int k = 0; k < NBn; k++) {
    const float x = goff[idx*NBn+k], lab = olab[idx*NBn+k];
    const float bce = lab * sp_(-x) + (1.f - lab) * sp_(x);
    offv = fmaf(binw[k], bce, offv);
  }
  offv *= (1.0f / NBn);
  const float sb = bsh[idx];
  const float sbce = sc * sp_(-sb) + (1.f - sc) * sp_(sb);

  float* part = ws + OFF_PART + (size_t)pb*8;
  float t;
  t = blockSum128_(cosd*sc, red); if (threadIdx.x == 0) part[0] = t;
  t = blockSum128_(cosa*sc, red); if (threadIdx.x == 0) part[1] = t;
  t = blockSum128_(offv*sc, red); if (threadIdx.x == 0) part[2] = t;
  t = blockSum128_(sc, red);      if (threadIdx.x == 0) part[3] = t;
  t = blockSum128_(sbce, red);    if (threadIdx.x == 0) part[4] = t;
}

// ---------- single-pass pairwise kernel. grid (Nn/TCOLS, Nn/NCH, Bn) = (8,16,4), block 256.
// Each lane owns 4 gt columns in registers. Sym distances via the permutation identity
// (sym = gt with pts 2<->3 swapped): dot_sym = dot_gt + (p[6..8]-p[9..11]).(g[9..11]-g[6..8]).
// 128 pred rows staged in LDS; norms ride in slot 15 -> only 4 broadcast ds_read_b128/j.
// Forward row-min via DPP (VALU pipe). __launch_bounds__(256,2) -> no spill (r8 lesson).
__global__ __launch_bounds__(256, 2) void k_pair(const float* __restrict__ succ,
                                                 float* __restrict__ ws) {
  __shared__ float pls[NCH*16];       // 128 pred rows x 16 floats (norm in slot 15)
  __shared__ unsigned bkey[TCOLS];
  const int tile = blockIdx.x * TCOLS, b = blockIdx.z;
  const int bN = b * Nn;
  const int ny0 = blockIdx.y * NCH;
  const int tid = threadIdx.x;
  const int lane = tid & 63;
  const int wid = __builtin_amdgcn_readfirstlane(tid >> 6);

  // stage pred rows: 512 float4s by 256 threads (2 each)
  {
    #pragma unroll
    for (int e = 0; e < 2; e++) {
      const int ent = e*256 + tid;
      const int row = ent >> 2, q = ent & 3;
      ((float4*)pls)[ent] = ((const float4*)(ws + OFF_PRED))[(size_t)(bN + ny0 + row)*4 + q];
    }
    bkey[tid] = 0xFFFFFFFFu;
  }

  // lane's four columns (registers); gq[c][3].w = gn2
  float4 gq[4][4];
  float  biasc[4], ex[4], ey[4], ez[4];
  unsigned kk[4];
  const float4* G = (const float4*)(ws + OFF_GT);
  #pragma unroll
  for (int c = 0; c < 4; c++) {
    const int r = bN + tile + c*64 + lane;
    gq[c][0] = G[(size_t)r*4+0]; gq[c][1] = G[(size_t)r*4+1];
    gq[c][2] = G[(size_t)r*4+2]; gq[c][3] = G[(size_t)r*4+3];
    biasc[c] = (succ[r] != 0.f) ? 0.f : BIGM;
    // sym-delta fragments: g[9..11] - g[6..8]
    ex[c] = gq[c][2].y - gq[c][1].z;
    ey[c] = gq[c][2].z - gq[c][1].w;
    ez[c] = gq[c][2].w - gq[c][2].x;
    kk[c] = 0xFFFFFFFFu;
  }
  __syncthreads();

  for (int p = 0; p < 2; p++) {                  // two 16-row passes per wave
    const int rbase = wid*32 + p*16;
    const float4* PL = (const float4*)pls + (size_t)rbase*4;
    float f[16];

    #pragma unroll
    for (int j = 0; j < 16; j++) {
      const float4 p0 = PL[j*4+0], p1 = PL[j*4+1], p2 = PL[j*4+2], p3 = PL[j*4+3];
      const float pn2 = p3.w;                    // norm packed in slot 15
      const float pd0 = p1.z - p2.y, pd1 = p1.w - p2.z, pd2 = p2.x - p2.w;
      const unsigned nl = (unsigned)(ny0 + rbase + j), nh = nl | 0x800u;

      float fj = BIGM * 2.f;
      #pragma unroll
      for (int c = 0; c < 4; c++) {
        float s;
        s = fmaf(p0.w, gq[c][0].w, fmaf(p0.z, gq[c][0].z, fmaf(p0.y, gq[c][0].y, p0.x*gq[c][0].x)));
        s = fmaf(p1.w, gq[c][1].w, fmaf(p1.z, gq[c][1].z, fmaf(p1.y, gq[c][1].y, fmaf(p1.x, gq[c][1].x, s))));
        s = fmaf(p2.w, gq[c][2].w, fmaf(p2.z, gq[c][2].z, fmaf(p2.y, gq[c][2].y, fmaf(p2.x, gq[c][2].x, s))));
        const float dot = fmaf(p3.z, gq[c][3].z, fmaf(p3.y, gq[c][3].y, fmaf(p3.x, gq[c][3].x, s)));
        const float del = fmaf(pd0, ex[c], fmaf(pd1, ey[c], pd2*ez[c]));
        const float q1  = fmaf(-2.f, dot, pn2 + gq[c][3].w);
        const float d1  = fmaxf(q1, 0.f);
        const float d2  = fmaxf(fmaf(-2.f, del, q1), 0.f);

        // backward packed key: (dist&0xFFFFF000)|(mat<<11)|n — u32 min is lexicographic
        // (d, mat, n): d-tie -> mat0 (= reference i1-on-tie), then first n.
        kk[c] = min(kk[c], min((__float_as_uint(d1) & 0xFFFFF000u) | nl,
                               (__float_as_uint(d2) & 0xFFFFF000u) | nh));

        fj = fminf(fj, fminf(d1, d2) + biasc[c]);
      }
      f[j] = fj;
    }

    // forward: 16 independent DPP wave-min chains (VALU pipe); lane 63 owns results
    #pragma unroll
    for (int j = 0; j < 16; j++) f[j] = waveMin_(f[j]);
    if (lane == 63) {
      #pragma unroll
      for (int j = 0; j < 16; j++)
        atomicMin((unsigned*)ws + OFF_BEST + bN + ny0 + rbase + j, __float_as_uint(f[j]));
    }
  }

  // merge the 4 waves' backward keys (same columns, disjoint n) then one global atomic/col
  #pragma unroll
  for (int c = 0; c < 4; c++) atomicMin(&bkey[c*64 + lane], kk[c]);
  __syncthreads();
  atomicMin((unsigned*)ws + OFF_PK + bN + tile + tid, bkey[tid]);
}

// ---------- fused reduce+finalize. grid (Nn/128, Bn) = (16,4) = 64 blocks, block 128.
// Each block writes its adds/g2p partials (record b*16+nt, fields 5,6 — same record
// index space as k_prep's). LAST block (device atomic counter) does the final combine.
__global__ __launch_bounds__(128) void k_redfin(const float* __restrict__ bsp,
                                                const float* __restrict__ succ,
                                                float* __restrict__ ws,
                                                float* __restrict__ out) {
  __shared__ float red[2];
  __shared__ int isLast;
  const int b = blockIdx.y, nt = blockIdx.x;
  const int idx = b*Nn + nt*128 + threadIdx.x;

  const float best = __uint_as_float(((const unsigned*)ws)[OFF_BEST + idx]);
  const float adds = (best < 1e30f) ? bsp[idx] * sqrtf(best) : 0.f;  // >=1e30 <=> no positives -> gate 0

  const unsigned key = ((const unsigned*)ws)[OFF_PK + idx];
  const float d = __uint_as_float(key & 0xFFFFF000u);
  const int  id = (int)(key & 0x7FFu);
  const float g2p = bsp[b*Nn + id] * d * succ[idx];

  float* part = ws + OFF_PART + (size_t)(b*16 + nt)*8;
  float t;
  t = blockSum128_(adds, red); if (threadIdx.x == 0) part[5] = t;
  t = blockSum128_(g2p, red);  if (threadIdx.x == 0) part[6] = t;

  // completion protocol: release fence -> count; last block acquires and finalizes
  __threadfence();
  if (threadIdx.x == 0)
    isLast = (atomicAdd((unsigned*)ws + OFF_CNT, 1u) == 63u);
  __syncthreads();
  if (!isLast) return;
  __threadfence();

  const int tt = threadIdx.x;
  if (tt >= 64) return;                           // wave 0 finalizes
  float v[7];
  #pragma unroll
  for (int c = 0; c < 7; c++) v[c] = ws[OFF_PART + tt*8 + c];
  // butterfly within 16-lane groups: every lane gets its batch-b sums (b = tt>>4)
  #pragma unroll
  for (int o = 1; o < 16; o <<= 1) {
    #pragma unroll
    for (int c = 0; c < 7; c++) v[c] += __shfl_xor(v[c], o, 64);
  }
  const float pos = fmaxf(v[3], 1.f);
  float vb   = (v[0] + v[1] + v[2] + v[6]) / pos;   // dir + app + off + g2p, per-b normalized
  float bce  = v[4];
  float adds2 = v[5];
  #pragma unroll
  for (int o = 16; o < 64; o <<= 1) {               // sum the 4 batches
    vb    += __shfl_xor(vb,    o, 64);
    bce   += __shfl_xor(bce,   o, 64);
    adds2 += __shfl_xor(adds2, o, 64);
  }
  if (tt == 0)
    out[0] = vb * 0.25f + bce * (1.f/BN) + 10.f * adds2 * (1.f/BN);
}

extern "C" void kernel_launch(void* const* d_in, const int* in_sizes, int n_in,
                              void* d_out, int out_size, void* d_ws, size_t ws_size,
                              hipStream_t stream) {
  const float* gdir  = (const float*)d_in[0];
  const float* adirp = (const float*)d_in[1];
  const float* goff  = (const float*)d_in[2];
  const float* ppts  = (const float*)d_in[3];
  const float* bsp   = (const float*)d_in[4];
  const float* bsh   = (const float*)d_in[5];
  const float* dlab  = (const float*)d_in[6];
  const float* olab  = (const float*)d_in[7];
  const float* succ  = (const float*)d_in[8];
  const float* alab  = (const float*)d_in[9];
  const float* binv  = (const float*)d_in[10];
  const float* binw  = (const float*)d_in[11];
  const float* cpts  = (const float*)d_in[12];
  const float* scpts = (const float*)d_in[13];
  float* ws  = (float*)d_ws;
  float* out = (float*)d_out;
  (void)scpts;

  k_prep<<<dim3(BN/128), dim3(128), 0, stream>>>(gdir, adirp, goff, ppts, bsh,
                                                 dlab, olab, succ, alab,
                                                 binv, binw, cpts, scpts, ws);
  k_pair<<<dim3(Nn/TCOLS, Nn/NCH, Bn), dim3(256), 0, stream>>>(succ, ws);
  k_redfin<<<dim3(Nn/128, Bn), dim3(128), 0, stream>>>(bsp, succ, ws, out);
}